// Round 9
// baseline (95.433 us; speedup 1.0000x reference)
//
#include <hip/hip_runtime.h>
#include <hip/hip_bf16.h>
#include <stdint.h>

#define M_DIM 2048
#define N_DIM 4096
#define K_DIM 4096

#define NT 64  // K tiles of 64

typedef short short8 __attribute__((ext_vector_type(8)));
typedef float f32x4 __attribute__((ext_vector_type(4)));

typedef __attribute__((address_space(1))) unsigned int gu32;
typedef __attribute__((address_space(3))) unsigned int lu32;

// f32 -> bf16 round-to-nearest-even
__device__ static inline unsigned short f32_to_bf16(float f) {
  union { float f; unsigned int u; } v; v.f = f;
  unsigned int u = v.u;
  u += 0x7FFFu + ((u >> 16) & 1u);
  return (unsigned short)(u >> 16);
}

// ---- x: f32 [M][K] -> bf16 [M][K] ----
__global__ void cvt_x_kernel(const float* __restrict__ in, unsigned short* __restrict__ out) {
  size_t i = ((size_t)blockIdx.x * blockDim.x + threadIdx.x) * 8;
  f32x4 a = *(const f32x4*)(in + i);
  f32x4 b = *(const f32x4*)(in + i + 4);
  short8 o;
  o[0] = (short)f32_to_bf16(a[0]); o[1] = (short)f32_to_bf16(a[1]);
  o[2] = (short)f32_to_bf16(a[2]); o[3] = (short)f32_to_bf16(a[3]);
  o[4] = (short)f32_to_bf16(b[0]); o[5] = (short)f32_to_bf16(b[1]);
  o[6] = (short)f32_to_bf16(b[2]); o[7] = (short)f32_to_bf16(b[3]);
  *(short8*)(out + i) = o;
}

// ---- w: f32 [K][N] -> bf16 Bt [N][K] ----
__global__ void transpose_cvt_w_kernel(const float* __restrict__ w, unsigned short* __restrict__ wt) {
  __shared__ unsigned short tile[64][64 + 8];
  int bn = blockIdx.x * 64;
  int bk = blockIdx.y * 64;
  int t = threadIdx.x;
  int c4 = (t & 15) * 4;
  int r0 = t >> 4;
#pragma unroll
  for (int p = 0; p < 4; ++p) {
    int r = r0 + p * 16;
    f32x4 v = *(const f32x4*)(w + (size_t)(bk + r) * N_DIM + bn + c4);
    tile[c4 + 0][r] = f32_to_bf16(v[0]);
    tile[c4 + 1][r] = f32_to_bf16(v[1]);
    tile[c4 + 2][r] = f32_to_bf16(v[2]);
    tile[c4 + 3][r] = f32_to_bf16(v[3]);
  }
  __syncthreads();
  int orow = t >> 2;
  int oc = (t & 3) * 16;
  short8 lo, hi;
#pragma unroll
  for (int j = 0; j < 8; ++j) {
    lo[j] = (short)tile[orow][oc + j];
    hi[j] = (short)tile[orow][oc + 8 + j];
  }
  unsigned short* op = wt + (size_t)(bn + orow) * K_DIM + bk + oc;
  *(short8*)(op) = lo;
  *(short8*)(op + 8) = hi;
}

// ========= GEMM (round 9): 128x128, 2 independent blocks per CU =========
// BM=BN=128, BK=64. 256 threads = 4 waves (2x2), wave tile 64x64.
// Grid 512 = 2 blocks/CU (LDS 64KB/block). Mechanism under test: the ~1400
// cyc/tile serial residual (barrier release + ds_read ramp + vmcnt drain)
// that R7/R8 proved insensitive to scheduling and traffic is HIDDEN by the
// sibling block's MFMA burst (R6 showed removing TLP costs hugely; this
// adds independent TLP). Side benefit: 4-wave 128^2 has the lowest sharing
// redundancy (64KB reads/tile = 15.3 B/KFLOP vs R4's 30.5).
// LDS: 2 sides x 32KB. Depth-1 prefetch: body t stages t+1 into side t^1,
// issued at TOP of body (max flight time ~1 tile). Top-of-tile
// {vmcnt(0) lgkmcnt(0); s_barrier} gives the proven invariants:
// RAW: my t loads done + published; WAR: all waves' t-1 reads done
// (lgkmcnt(0) before barrier) before anyone stages into side t^1 = (t-1)&1.
// XOR swizzle identical (slot = chunk ^ (row&7)); conflicts stay 0.

__global__ __launch_bounds__(256) void gemm2b_kernel(
    const unsigned short* __restrict__ A, const unsigned short* __restrict__ Bt,
    const float* __restrict__ bias, float* __restrict__ C) {
  __shared__ unsigned short sm[2 * 16384];  // 65536 B
  char* smemc = (char*)&sm[0];

  const int tid = threadIdx.x;
  const int lane = tid & 63;
  const int w = tid >> 6;              // 0..3
  const int wm = w >> 1, wn = w & 1;   // 2x2 wave grid

  // 512-block remap: 8x8 region per XCD (bijective: by 0..15, bx 0..31)
  const int id = blockIdx.x;
  const int xcd = id & 7, j = id >> 3;
  const int by = ((xcd >> 2) << 3) + (j >> 3);
  const int bx = ((xcd & 3) << 3) + (j & 7);
  const int r0 = by * 128, c0 = bx * 128;

  // ---- staging precompute (pre-swizzled global source, linear LDS dest) ----
  const int l8 = lane >> 3, l7 = lane & 7;
  const int chunkE = ((l7 ^ l8) << 3);  // swizzled k-chunk (bf16 elems), row&7 == l8
  const unsigned short* Ag = A + (size_t)(r0 + w * 32 + l8) * K_DIM + chunkE;
  const unsigned short* Bg = Bt + (size_t)(c0 + w * 32 + l8) * K_DIM + chunkE;

#define GL(gp, ldsoff) __builtin_amdgcn_global_load_lds((gu32*)(gp), (lu32*)(smemc + (ldsoff)), 16, 0, 0)
  // wave w stages A rows [w*32,w*32+32) and B rows [w*32,w*32+32): 8 GLs/thread
#define STAGE(T, sb)                                                        \
  do {                                                                      \
    _Pragma("unroll") for (int i = 0; i < 4; ++i)                           \
        GL(Ag + (size_t)(T) * 64 + (size_t)i * 8 * K_DIM,                   \
           (sb) + w * 4096 + i * 1024);                                     \
    _Pragma("unroll") for (int i = 0; i < 4; ++i)                           \
        GL(Bg + (size_t)(T) * 64 + (size_t)i * 8 * K_DIM,                   \
           (sb) + 16384 + w * 4096 + i * 1024);                             \
  } while (0)

  // ---- fragment-read precompute (ushort units within side) ----
  const int l15 = lane & 15, hi = lane >> 4;
  const int aR = (wm * 64 + l15) * 64;         // A row base
  const int bR = 8192 + (wn * 64 + l15) * 64;  // B row base (B region at 16KB)
  const int slot0 = ((hi ^ l7) << 3);          // ks=0: chunk hi at slot hi^(row&7)
  const int slot1 = (((4 + hi) ^ l7) << 3);    // ks=1: chunk 4+hi

  f32x4 acc[4][4] = {};

  // prologue: stage tile 0 into side 0
  STAGE(0, 0);

  int cs = 0;  // side of tile t
  for (int t = 0; t < NT; ++t) {
    const int sE = cs * 16384;        // compute side (ushorts)
    const int stB = (cs ^ 1) * 32768; // stage side (bytes)

    // drain my tile-t loads + my t-1 reads; publish to all 4 waves
    asm volatile("s_waitcnt vmcnt(0) lgkmcnt(0)" ::: "memory");
    __builtin_amdgcn_sched_barrier(0);
    asm volatile("s_barrier" ::: "memory");

    // issue next tile's staging FIRST (max in-flight time)
    if (t + 1 < NT) STAGE(t + 1, stB);

    // ks=0 fragments + MFMA, then ks=1 (compiler pipelines the reads)
    short8 a0[4], b0[4];
#pragma unroll
    for (int m = 0; m < 4; ++m) a0[m] = *(const short8*)(sm + sE + aR + m * 1024 + slot0);
#pragma unroll
    for (int n = 0; n < 4; ++n) b0[n] = *(const short8*)(sm + sE + bR + n * 1024 + slot0);
    __builtin_amdgcn_s_setprio(1);
#pragma unroll
    for (int m = 0; m < 4; ++m)
#pragma unroll
      for (int n = 0; n < 4; ++n)
        acc[m][n] = __builtin_amdgcn_mfma_f32_16x16x32_bf16(a0[m], b0[n], acc[m][n], 0, 0, 0);
    __builtin_amdgcn_s_setprio(0);

    short8 a1[4], b1[4];
#pragma unroll
    for (int m = 0; m < 4; ++m) a1[m] = *(const short8*)(sm + sE + aR + m * 1024 + slot1);
#pragma unroll
    for (int n = 0; n < 4; ++n) b1[n] = *(const short8*)(sm + sE + bR + n * 1024 + slot1);
    __builtin_amdgcn_s_setprio(1);
#pragma unroll
    for (int m = 0; m < 4; ++m)
#pragma unroll
      for (int n = 0; n < 4; ++n)
        acc[m][n] = __builtin_amdgcn_mfma_f32_16x16x32_bf16(a1[m], b1[n], acc[m][n], 0, 0, 0);
    __builtin_amdgcn_s_setprio(0);

    cs ^= 1;
  }

  // ---- epilogue: fxp(y) + fxp(b), relu (R1-proven mapping) ----
  const float S = 65536.0f, IS = 1.0f / 65536.0f;
  const int lr = hi * 4;  // C/D: row=(lane>>4)*4+reg, col=lane&15
#pragma unroll
  for (int n = 0; n < 4; ++n) {
    int gcol = c0 + wn * 64 + n * 16 + l15;
    float bq = rintf(bias[gcol] * S) * IS;
#pragma unroll
    for (int m = 0; m < 4; ++m) {
      int grow = r0 + wm * 64 + m * 16 + lr;
      float* outp = C + (size_t)grow * N_DIM + gcol;
#pragma unroll
      for (int r = 0; r < 4; ++r) {
        float t = rintf(acc[m][n][r] * S) * IS + bq;
        t = t > 0.0f ? t : 0.0f;
        outp[(size_t)r * N_DIM] = t;
      }
    }
  }
#undef GL
#undef STAGE
}

// ---- fallback (small workspace): round-1 reg-staged kernel ----
__global__ __launch_bounds__(256, 2) void gemm_fb_kernel(
    const float* __restrict__ Xf, const float* __restrict__ Wf,
    const float* __restrict__ bias, float* __restrict__ C) {
  __shared__ unsigned short As[128][64];
  __shared__ unsigned short Bs[128][64];
  int tid = threadIdx.x;
  int lane = tid & 63;
  int wid = tid >> 6;
  int wr = wid >> 1, wc = wid & 1;
  int r0 = blockIdx.y * 128;
  int c0 = blockIdx.x * 128;
  f32x4 acc[4][4] = {};
  for (int kt = 0; kt < K_DIM / 64; ++kt) {
    __syncthreads();
    int ar = tid >> 1;
    int ac = (tid & 1) * 32;
    const float* xp = Xf + (size_t)(r0 + ar) * K_DIM + kt * 64 + ac;
#pragma unroll
    for (int jj = 0; jj < 8; ++jj) {
      f32x4 v = *(const f32x4*)(xp + jj * 4);
      As[ar][ac + jj * 4 + 0] = f32_to_bf16(v[0]);
      As[ar][ac + jj * 4 + 1] = f32_to_bf16(v[1]);
      As[ar][ac + jj * 4 + 2] = f32_to_bf16(v[2]);
      As[ar][ac + jj * 4 + 3] = f32_to_bf16(v[3]);
    }
    int bk_ = tid >> 2;
    int bc = (tid & 3) * 32;
    const float* wp = Wf + (size_t)(kt * 64 + bk_) * N_DIM + c0 + bc;
#pragma unroll
    for (int jj = 0; jj < 8; ++jj) {
      f32x4 v = *(const f32x4*)(wp + jj * 4);
      Bs[bc + jj * 4 + 0][bk_] = f32_to_bf16(v[0]);
      Bs[bc + jj * 4 + 1][bk_] = f32_to_bf16(v[1]);
      Bs[bc + jj * 4 + 2][bk_] = f32_to_bf16(v[2]);
      Bs[bc + jj * 4 + 3][bk_] = f32_to_bf16(v[3]);
    }
    __syncthreads();
#pragma unroll
    for (int ks = 0; ks < 2; ++ks) {
      int co = ks * 32 + (lane >> 4) * 8;
      int rA = wr * 64 + (lane & 15);
      int rB = wc * 64 + (lane & 15);
      short8 a[4], b[4];
#pragma unroll
      for (int m = 0; m < 4; ++m) a[m] = *(const short8*)&As[rA + m * 16][co];
#pragma unroll
      for (int n = 0; n < 4; ++n) b[n] = *(const short8*)&Bs[rB + n * 16][co];
#pragma unroll
      for (int m = 0; m < 4; ++m)
#pragma unroll
        for (int n = 0; n < 4; ++n)
          acc[m][n] = __builtin_amdgcn_mfma_f32_16x16x32_bf16(a[m], b[n], acc[m][n], 0, 0, 0);
    }
  }
  const float S = 65536.0f, IS = 1.0f / 65536.0f;
  int lr = (lane >> 4) * 4;
  int lc = lane & 15;
#pragma unroll
  for (int n = 0; n < 4; ++n) {
    int gcol = c0 + wc * 64 + n * 16 + lc;
    float bq = rintf(bias[gcol] * S) * IS;
#pragma unroll
    for (int m = 0; m < 4; ++m) {
      int grow = r0 + wr * 64 + m * 16 + lr;
      float* outp = C + (size_t)grow * N_DIM + gcol;
#pragma unroll
      for (int r = 0; r < 4; ++r) {
        float t = rintf(acc[m][n][r] * S) * IS + bq;
        t = t > 0.0f ? t : 0.0f;
        outp[(size_t)r * N_DIM] = t;
      }
    }
  }
}

extern "C" void kernel_launch(void* const* d_in, const int* in_sizes, int n_in,
                              void* d_out, int out_size, void* d_ws, size_t ws_size,
                              hipStream_t stream) {
  const float* x = (const float*)d_in[0];
  const float* w = (const float*)d_in[1];
  const float* b = (const float*)d_in[2];
  float* out = (float*)d_out;

  size_t needA = (size_t)M_DIM * K_DIM * sizeof(unsigned short);
  size_t needB = (size_t)K_DIM * N_DIM * sizeof(unsigned short);

  if (ws_size >= needA + needB) {
    unsigned short* Abf = (unsigned short*)d_ws;
    unsigned short* Btbf = (unsigned short*)((char*)d_ws + needA);
    cvt_x_kernel<<<(M_DIM * (size_t)K_DIM / 8 + 255) / 256, 256, 0, stream>>>(x, Abf);
    transpose_cvt_w_kernel<<<dim3(N_DIM / 64, K_DIM / 64), 256, 0, stream>>>(w, Btbf);
    gemm2b_kernel<<<512, 256, 0, stream>>>(Abf, Btbf, b, out);
  } else {
    gemm_fb_kernel<<<dim3(N_DIM / 128, M_DIM / 128), 256, 0, stream>>>(x, w, b, out);
  }
}

// Round 10
// 91.287 us; speedup vs baseline: 1.0454x; 1.0454x over previous
//
#include <hip/hip_runtime.h>
#include <hip/hip_bf16.h>
#include <stdint.h>

#define M_DIM 2048
#define N_DIM 4096
#define K_DIM 4096

#define NT 64  // K tiles of 64

typedef short short8 __attribute__((ext_vector_type(8)));
typedef float f32x4 __attribute__((ext_vector_type(4)));

typedef __attribute__((address_space(1))) unsigned int gu32;
typedef __attribute__((address_space(3))) unsigned int lu32;

// f32 -> bf16 round-to-nearest-even
__device__ static inline unsigned short f32_to_bf16(float f) {
  union { float f; unsigned int u; } v; v.f = f;
  unsigned int u = v.u;
  u += 0x7FFFu + ((u >> 16) & 1u);
  return (unsigned short)(u >> 16);
}

// ---- x: f32 [M][K] -> bf16 [M][K] ----
__global__ void cvt_x_kernel(const float* __restrict__ in, unsigned short* __restrict__ out) {
  size_t i = ((size_t)blockIdx.x * blockDim.x + threadIdx.x) * 8;
  f32x4 a = *(const f32x4*)(in + i);
  f32x4 b = *(const f32x4*)(in + i + 4);
  short8 o;
  o[0] = (short)f32_to_bf16(a[0]); o[1] = (short)f32_to_bf16(a[1]);
  o[2] = (short)f32_to_bf16(a[2]); o[3] = (short)f32_to_bf16(a[3]);
  o[4] = (short)f32_to_bf16(b[0]); o[5] = (short)f32_to_bf16(b[1]);
  o[6] = (short)f32_to_bf16(b[2]); o[7] = (short)f32_to_bf16(b[3]);
  *(short8*)(out + i) = o;
}

// ---- w: f32 [K][N] -> bf16 Bt [N][K] ----
__global__ void transpose_cvt_w_kernel(const float* __restrict__ w, unsigned short* __restrict__ wt) {
  __shared__ unsigned short tile[64][64 + 8];
  int bn = blockIdx.x * 64;
  int bk = blockIdx.y * 64;
  int t = threadIdx.x;
  int c4 = (t & 15) * 4;
  int r0 = t >> 4;
#pragma unroll
  for (int p = 0; p < 4; ++p) {
    int r = r0 + p * 16;
    f32x4 v = *(const f32x4*)(w + (size_t)(bk + r) * N_DIM + bn + c4);
    tile[c4 + 0][r] = f32_to_bf16(v[0]);
    tile[c4 + 1][r] = f32_to_bf16(v[1]);
    tile[c4 + 2][r] = f32_to_bf16(v[2]);
    tile[c4 + 3][r] = f32_to_bf16(v[3]);
  }
  __syncthreads();
  int orow = t >> 2;
  int oc = (t & 3) * 16;
  short8 lo, hi;
#pragma unroll
  for (int j = 0; j < 8; ++j) {
    lo[j] = (short)tile[orow][oc + j];
    hi[j] = (short)tile[orow][oc + 8 + j];
  }
  unsigned short* op = wt + (size_t)(bn + orow) * K_DIM + bk + oc;
  *(short8*)(op) = lo;
  *(short8*)(op + 8) = hi;
}

// ====== GEMM (round 10): 2-tile windows, 1 barrier/tile, free-run ======
// BM=128, BN=256, BK=64. 512 threads = 8 waves (2M x 4N), wave tile 64x64.
// LDS: 3 sides x 48KB. Window jw handles tiles {t=2jw, t+1}; sides rotate
// by 2 per window: side(T) = T%3. Staging: t+2 -> side cs2=(cs+2)%3 in
// half 1; t+3 -> side cs (tile t's side, freed at mid barrier) in half 2.
// Sync (2 points per window = 1 barrier/tile):
//   top: vmcnt(0) lgkmcnt(0); s_barrier  -- t,t+1 staged & published (RAW);
//        side cs2's readers (prev window half 2) drained (WAR).
//   mid: lgkmcnt(0); s_barrier -- all waves' side-cs reads complete, so
//        half 2's GL(t+3 -> cs) is WAR-safe chip-wide (round-2 invariant).
// Between sync points: ~1300-cyc free-run {ds_read + GL + MFMA} segments;
// waves drift apart so the LDS port streams concurrently with MFMA instead
// of alternating in lockstep bursts (R3-R9 all pinned at ~2700 cyc/tile;
// m201 evidence: 78 B/cyc port sustained WITH 75% MFMA issue occupancy).
// XOR swizzle / staging / fragment maps / epilogue identical to R4 (proven).

__global__ __launch_bounds__(512) void gemm8_kernel(
    const unsigned short* __restrict__ A, const unsigned short* __restrict__ Bt,
    const float* __restrict__ bias, float* __restrict__ C) {
  __shared__ unsigned short smA[3 * 24576];  // 147456 B
  char* smemc = (char*)&smA[0];

  const int tid = threadIdx.x;
  const int lane = tid & 63;
  const int w = tid >> 6;
  const int wm = w >> 2, wn = w & 3;

  // 8x4 region remap for L2 locality (bijective over 256 blocks)
  const int id = blockIdx.x;
  const int x = id & 7, j = id >> 3;
  const int by = ((x >> 2) << 3) + (j >> 2);
  const int bx = ((x & 3) << 2) + (j & 3);
  const int r0 = by * 128, c0 = bx * 256;

  // ---- staging precompute (pre-swizzled global source, linear LDS dest) ----
  const int l8 = lane >> 3, l7 = lane & 7;
  const int chunkE = ((l7 ^ l8) << 3);  // swizzled k-chunk (bf16 elems), row&7 == l8
  const unsigned short* Ag = A + (size_t)(r0 + w * 16 + l8) * K_DIM + chunkE;
  const unsigned short* Bg = Bt + (size_t)(c0 + w * 32 + l8) * K_DIM + chunkE;
  const int aL0 = w * 2048;          // byte offset of wave's A chunk within side
  const int bL0 = 16384 + w * 4096;  // byte offset of wave's B chunk within side

#define GL(gp, ldsoff) __builtin_amdgcn_global_load_lds((gu32*)(gp), (lu32*)(smemc + (ldsoff)), 16, 0, 0)
#define STAGE_ALL(t, sb)                                               \
  do {                                                                 \
    GL(Ag + (size_t)(t) * 64, (sb) + aL0);                             \
    GL(Ag + (size_t)(t) * 64 + 8 * (size_t)K_DIM, (sb) + aL0 + 1024);  \
    GL(Bg + (size_t)(t) * 64, (sb) + bL0);                             \
    GL(Bg + (size_t)(t) * 64 + 8 * (size_t)K_DIM, (sb) + bL0 + 1024);  \
    GL(Bg + (size_t)(t) * 64 + 16 * (size_t)K_DIM, (sb) + bL0 + 2048); \
    GL(Bg + (size_t)(t) * 64 + 24 * (size_t)K_DIM, (sb) + bL0 + 3072); \
  } while (0)

  // ---- fragment-read precompute: 12 base pointers (side x ks x {A,B}) ----
  const int l15 = lane & 15, hi = lane >> 4;
  const int aR = (wm * 64 + l15) * 64;         // A row base (ushorts)
  const int bR = 8192 + (wn * 64 + l15) * 64;  // B row base (B region at 16KB)
  const int slot0 = ((hi ^ l7) << 3);          // ks=0: chunk hi at slot hi^(row&7)
  const int slot1 = (((4 + hi) ^ l7) << 3);    // ks=1: chunk 4+hi
  const unsigned short* pA[3][2];
  const unsigned short* pB[3][2];
#pragma unroll
  for (int s = 0; s < 3; ++s) {
    pA[s][0] = smA + s * 24576 + aR + slot0;
    pA[s][1] = smA + s * 24576 + aR + slot1;
    pB[s][0] = smA + s * 24576 + bR + slot0;
    pB[s][1] = smA + s * 24576 + bR + slot1;
  }

  f32x4 acc[4][4] = {};

  // prologue: stage tiles 0 and 1
  STAGE_ALL(0, 0);
  STAGE_ALL(1, 49152);

  int cs = 0;  // side of tile t (cycles 0,2,1,0,...: +2 mod 3 per window)
  for (int jw = 0; jw < NT / 2; ++jw) {
    const int t = jw * 2;
    const int cs1 = (cs == 2) ? 0 : cs + 1;
    const int cs2 = (cs1 == 2) ? 0 : cs1 + 1;
    const bool doS = (t + 2) < NT;

    const unsigned short* pAs0 = (cs == 0) ? pA[0][0] : (cs == 1) ? pA[1][0] : pA[2][0];
    const unsigned short* pAs1 = (cs == 0) ? pA[0][1] : (cs == 1) ? pA[1][1] : pA[2][1];
    const unsigned short* pBs0 = (cs == 0) ? pB[0][0] : (cs == 1) ? pB[1][0] : pB[2][0];
    const unsigned short* pBs1 = (cs == 0) ? pB[0][1] : (cs == 1) ? pB[1][1] : pB[2][1];
    const unsigned short* qAs0 = (cs1 == 0) ? pA[0][0] : (cs1 == 1) ? pA[1][0] : pA[2][0];
    const unsigned short* qAs1 = (cs1 == 0) ? pA[0][1] : (cs1 == 1) ? pA[1][1] : pA[2][1];
    const unsigned short* qBs0 = (cs1 == 0) ? pB[0][0] : (cs1 == 1) ? pB[1][0] : pB[2][0];
    const unsigned short* qBs1 = (cs1 == 0) ? pB[0][1] : (cs1 == 1) ? pB[1][1] : pB[2][1];

    // ---- window top: tiles t,t+1 staged everywhere; side cs2 free ----
    asm volatile("s_waitcnt vmcnt(0) lgkmcnt(0)" ::: "memory");
    asm volatile("s_barrier" ::: "memory");

    // ---- half 1: tile t (side cs), stage t+2 -> side cs2 ----
    {
      short8 a0[4], b0[4], a1[4], b1[4];
#pragma unroll
      for (int m = 0; m < 4; ++m) a0[m] = *(const short8*)(pAs0 + m * 1024);
#pragma unroll
      for (int n = 0; n < 4; ++n) b0[n] = *(const short8*)(pBs0 + n * 1024);
      if (doS) STAGE_ALL(t + 2, cs2 * 49152);
#pragma unroll
      for (int m = 0; m < 4; ++m) a1[m] = *(const short8*)(pAs1 + m * 1024);
#pragma unroll
      for (int n = 0; n < 4; ++n) b1[n] = *(const short8*)(pBs1 + n * 1024);

      __builtin_amdgcn_s_setprio(1);
#pragma unroll
      for (int m = 0; m < 4; ++m)
#pragma unroll
        for (int n = 0; n < 4; ++n)
          acc[m][n] = __builtin_amdgcn_mfma_f32_16x16x32_bf16(a0[m], b0[n], acc[m][n], 0, 0, 0);
#pragma unroll
      for (int m = 0; m < 4; ++m)
#pragma unroll
        for (int n = 0; n < 4; ++n)
          acc[m][n] = __builtin_amdgcn_mfma_f32_16x16x32_bf16(a1[m], b1[n], acc[m][n], 0, 0, 0);
      __builtin_amdgcn_s_setprio(0);
    }

    // ---- mid: all waves' side-cs reads complete -> cs reusable ----
    asm volatile("s_waitcnt lgkmcnt(0)" ::: "memory");
    asm volatile("s_barrier" ::: "memory");

    // ---- half 2: tile t+1 (side cs1), stage t+3 -> side cs ----
    {
      if (doS) STAGE_ALL(t + 3, cs * 49152);
      short8 a0[4], b0[4], a1[4], b1[4];
#pragma unroll
      for (int m = 0; m < 4; ++m) a0[m] = *(const short8*)(qAs0 + m * 1024);
#pragma unroll
      for (int n = 0; n < 4; ++n) b0[n] = *(const short8*)(qBs0 + n * 1024);
#pragma unroll
      for (int m = 0; m < 4; ++m) a1[m] = *(const short8*)(qAs1 + m * 1024);
#pragma unroll
      for (int n = 0; n < 4; ++n) b1[n] = *(const short8*)(qBs1 + n * 1024);

      __builtin_amdgcn_s_setprio(1);
#pragma unroll
      for (int m = 0; m < 4; ++m)
#pragma unroll
        for (int n = 0; n < 4; ++n)
          acc[m][n] = __builtin_amdgcn_mfma_f32_16x16x32_bf16(a0[m], b0[n], acc[m][n], 0, 0, 0);
#pragma unroll
      for (int m = 0; m < 4; ++m)
#pragma unroll
        for (int n = 0; n < 4; ++n)
          acc[m][n] = __builtin_amdgcn_mfma_f32_16x16x32_bf16(a1[m], b1[n], acc[m][n], 0, 0, 0);
      __builtin_amdgcn_s_setprio(0);
    }

    cs = cs2;
  }

  // ---- epilogue: fxp(y) + fxp(b), relu ----
  const float S = 65536.0f, IS = 1.0f / 65536.0f;
  const int lr = hi * 4;  // C/D: row=(lane>>4)*4+reg, col=lane&15
#pragma unroll
  for (int n = 0; n < 4; ++n) {
    int gcol = c0 + wn * 64 + n * 16 + l15;
    float bq = rintf(bias[gcol] * S) * IS;
#pragma unroll
    for (int m = 0; m < 4; ++m) {
      int grow = r0 + wm * 64 + m * 16 + lr;
      float* outp = C + (size_t)grow * N_DIM + gcol;
#pragma unroll
      for (int r = 0; r < 4; ++r) {
        float t = rintf(acc[m][n][r] * S) * IS + bq;
        t = t > 0.0f ? t : 0.0f;
        outp[(size_t)r * N_DIM] = t;
      }
    }
  }
#undef GL
#undef STAGE_ALL
}

// ---- fallback (small workspace): round-1 reg-staged kernel ----
__global__ __launch_bounds__(256, 2) void gemm_fb_kernel(
    const float* __restrict__ Xf, const float* __restrict__ Wf,
    const float* __restrict__ bias, float* __restrict__ C) {
  __shared__ unsigned short As[128][64];
  __shared__ unsigned short Bs[128][64];
  int tid = threadIdx.x;
  int lane = tid & 63;
  int wid = tid >> 6;
  int wr = wid >> 1, wc = wid & 1;
  int r0 = blockIdx.y * 128;
  int c0 = blockIdx.x * 128;
  f32x4 acc[4][4] = {};
  for (int kt = 0; kt < K_DIM / 64; ++kt) {
    __syncthreads();
    int ar = tid >> 1;
    int ac = (tid & 1) * 32;
    const float* xp = Xf + (size_t)(r0 + ar) * K_DIM + kt * 64 + ac;
#pragma unroll
    for (int jj = 0; jj < 8; ++jj) {
      f32x4 v = *(const f32x4*)(xp + jj * 4);
      As[ar][ac + jj * 4 + 0] = f32_to_bf16(v[0]);
      As[ar][ac + jj * 4 + 1] = f32_to_bf16(v[1]);
      As[ar][ac + jj * 4 + 2] = f32_to_bf16(v[2]);
      As[ar][ac + jj * 4 + 3] = f32_to_bf16(v[3]);
    }
    int bk_ = tid >> 2;
    int bc = (tid & 3) * 32;
    const float* wp = Wf + (size_t)(kt * 64 + bk_) * N_DIM + c0 + bc;
#pragma unroll
    for (int jj = 0; jj < 8; ++jj) {
      f32x4 v = *(const f32x4*)(wp + jj * 4);
      Bs[bc + jj * 4 + 0][bk_] = f32_to_bf16(v[0]);
      Bs[bc + jj * 4 + 1][bk_] = f32_to_bf16(v[1]);
      Bs[bc + jj * 4 + 2][bk_] = f32_to_bf16(v[2]);
      Bs[bc + jj * 4 + 3][bk_] = f32_to_bf16(v[3]);
    }
    __syncthreads();
#pragma unroll
    for (int ks = 0; ks < 2; ++ks) {
      int co = ks * 32 + (lane >> 4) * 8;
      int rA = wr * 64 + (lane & 15);
      int rB = wc * 64 + (lane & 15);
      short8 a[4], b[4];
#pragma unroll
      for (int m = 0; m < 4; ++m) a[m] = *(const short8*)&As[rA + m * 16][co];
#pragma unroll
      for (int n = 0; n < 4; ++n) b[n] = *(const short8*)&Bs[rB + n * 16][co];
#pragma unroll
      for (int m = 0; m < 4; ++m)
#pragma unroll
        for (int n = 0; n < 4; ++n)
          acc[m][n] = __builtin_amdgcn_mfma_f32_16x16x32_bf16(a[m], b[n], acc[m][n], 0, 0, 0);
    }
  }
  const float S = 65536.0f, IS = 1.0f / 65536.0f;
  int lr = (lane >> 4) * 4;
  int lc = lane & 15;
#pragma unroll
  for (int n = 0; n < 4; ++n) {
    int gcol = c0 + wc * 64 + n * 16 + lc;
    float bq = rintf(bias[gcol] * S) * IS;
#pragma unroll
    for (int m = 0; m < 4; ++m) {
      int grow = r0 + wr * 64 + m * 16 + lr;
      float* outp = C + (size_t)grow * N_DIM + gcol;
#pragma unroll
      for (int r = 0; r < 4; ++r) {
        float t = rintf(acc[m][n][r] * S) * IS + bq;
        t = t > 0.0f ? t : 0.0f;
        outp[(size_t)r * N_DIM] = t;
      }
    }
  }
}

extern "C" void kernel_launch(void* const* d_in, const int* in_sizes, int n_in,
                              void* d_out, int out_size, void* d_ws, size_t ws_size,
                              hipStream_t stream) {
  const float* x = (const float*)d_in[0];
  const float* w = (const float*)d_in[1];
  const float* b = (const float*)d_in[2];
  float* out = (float*)d_out;

  size_t needA = (size_t)M_DIM * K_DIM * sizeof(unsigned short);
  size_t needB = (size_t)K_DIM * N_DIM * sizeof(unsigned short);

  if (ws_size >= needA + needB) {
    unsigned short* Abf = (unsigned short*)d_ws;
    unsigned short* Btbf = (unsigned short*)((char*)d_ws + needA);
    cvt_x_kernel<<<(M_DIM * (size_t)K_DIM / 8 + 255) / 256, 256, 0, stream>>>(x, Abf);
    transpose_cvt_w_kernel<<<dim3(N_DIM / 64, K_DIM / 64), 256, 0, stream>>>(w, Btbf);
    gemm8_kernel<<<256, 512, 0, stream>>>(Abf, Btbf, b, out);
  } else {
    gemm_fb_kernel<<<dim3(N_DIM / 128, M_DIM / 128), 256, 0, stream>>>(x, w, b, out);
  }
}